// Round 7
// baseline (119.275 us; speedup 1.0000x reference)
//
#include <hip/hip_runtime.h>

typedef __attribute__((ext_vector_type(8))) short short8;
typedef __attribute__((ext_vector_type(4))) float float4_t;

#define NB 32
#define NL 256
#define ND 128
#define OUT_PLANE (NB * ND * NL)   // elements per stacked output plane
#define XS 136                     // LDS row stride (bf16): bw-floor reads
#define BUFSZ (18 * XS)
#define FR_WORD 49152              // word-frag offset in ws (bf16 units)
#define CHRB 98304                 // bf16 chr_table offset in ws (bf16 units)

__device__ inline unsigned short f2bf(float f) {
    union { float f; unsigned int i; } c;
    c.f = f;
    unsigned int r = c.i + 0x7FFFu + ((c.i >> 16) & 1u);  // RN-even
    return (unsigned short)(r >> 16);
}

// ---------------------------------------------------------------------------
// ws prep: [0..49151] char B-frags, [49152..98303] word B-frags,
// [98304..114687] chr_table converted to bf16 (row 0 stays all-zero).
// Frag order: frag[s][nt][lane][j]; B[k'][n]: n=lane&15, k'=s*32+(lane>>4)*8+j,
// tap t=s>>2, k=(s&3)*32+(lane>>4)*8+j.  Value = W[dout][k][t].
// ---------------------------------------------------------------------------
__global__ void make_frags(const float* __restrict__ Wc,
                           const float* __restrict__ Ww,
                           const float* __restrict__ chrT,
                           unsigned short* __restrict__ out) {
    int i = blockIdx.x * 256 + threadIdx.x;            // 0..114687
    if (i < CHRB) {
        const float* W = (i < FR_WORD) ? Wc : Ww;
        int ii = (i < FR_WORD) ? i : i - FR_WORD;
        int j    = ii & 7;
        int lane = (ii >> 3) & 63;
        int nt   = (ii >> 9) & 7;
        int s    = ii >> 12;
        int dout = nt * 16 + (lane & 15);
        int t    = s >> 2;
        int k    = (s & 3) * 32 + ((lane >> 4) & 3) * 8 + j;
        out[i] = f2bf(W[(dout * 128 + k) * 3 + t]);
    } else {
        int j = i - CHRB;                              // 0..16383
        out[i] = f2bf(chrT[j]);
    }
}

// ---------------------------------------------------------------------------
// Single-wave conv kernel (64 thr/block, __launch_bounds__(64,1) -> full
// 512-reg file, 1 wave/SIMD). Each wave holds ALL 8 dout-ntiles resident
// (bfrag[12][8] = 384 VGPRs) and owns its LDS buffers -> ZERO barriers.
// Blocks 0..511: word path (1 tile of 16 l). Blocks 512..1535: char path
// (8 words, wave-private double-buffered staging from bf16 chr_table).
// ---------------------------------------------------------------------------
__global__ __launch_bounds__(64, 1) void conv_kernel(
    const int* __restrict__ wv, const int* __restrict__ wic,
    const float* __restrict__ wordT,
    const unsigned short* __restrict__ ws,
    const float* __restrict__ biasC, const float* __restrict__ biasW,
    float* __restrict__ out) {
    __shared__ unsigned short Xs[2 * BUFSZ];
    const int lane = threadIdx.x;
    const int m = lane & 15, quad = lane >> 4;
    const int bid = blockIdx.x;

    if (bid >= 512) {
        // ------------------------- char path -------------------------------
        const unsigned short* chrB = ws + CHRB;
        const int w0 = (bid - 512) * 8;   // 8 consecutive words, same b
        const int b = w0 >> 8;
        short8 bfrag[12][8];
#pragma unroll
        for (int s = 0; s < 12; ++s)
#pragma unroll
            for (int p = 0; p < 8; ++p)
                bfrag[s][p] = *(const short8*)(
                    ws + (((s * 8 + p) * 64 + lane) << 3));

        // zero pad rows (c=-1 and c=16) in both buffers; never overwritten
        for (int p = lane; p < XS; p += 64) {
            Xs[p] = 0; Xs[17 * XS + p] = 0;
            Xs[BUFSZ + p] = 0; Xs[BUFSZ + 17 * XS + p] = 0;
        }

        // staging map: lane covers rows quad+4q (q=0..3), 16B chunk m
        int nidx[4];
        {   // prologue: stage word 0 into buf0; prefetch idx of word 1
            int cidx[4];
#pragma unroll
            for (int q = 0; q < 4; ++q) cidx[q] = wic[w0 * 16 + quad + 4 * q];
            short8 g[4];
#pragma unroll
            for (int q = 0; q < 4; ++q)
                g[q] = *(const short8*)(chrB + cidx[q] * 128 + m * 8);
#pragma unroll
            for (int q = 0; q < 4; ++q)
                *(short8*)&Xs[(quad + 4 * q + 1) * XS + m * 8] = g[q];
#pragma unroll
            for (int q = 0; q < 4; ++q)
                nidx[q] = wic[(w0 + 1) * 16 + quad + 4 * q];
        }

        for (int j = 0; j < 8; ++j) {   // not unrolled: keep I-cache small
            unsigned short* bufC = &Xs[(j & 1) * BUFSZ];
            unsigned short* bufN = &Xs[((j + 1) & 1) * BUFSZ];

            // issue next word's gathers early (hidden under 96 MFMAs)
            short8 g[4];
            if (j < 7) {
#pragma unroll
                for (int q = 0; q < 4; ++q)
                    g[q] = *(const short8*)(chrB + nidx[q] * 128 + m * 8);
            }
            int tindx[4];
            if (j < 6) {
#pragma unroll
                for (int q = 0; q < 4; ++q)
                    tindx[q] = wic[(w0 + j + 2) * 16 + quad + 4 * q];
            }

            float4_t acc[8];
#pragma unroll
            for (int p = 0; p < 8; ++p) acc[p] = (float4_t){0.f,0.f,0.f,0.f};
#pragma unroll
            for (int s = 0; s < 12; ++s) {
                short8 a = *(const short8*)&bufC[(m + (s >> 2)) * XS +
                                                 (s & 3) * 32 + quad * 8];
#pragma unroll
                for (int p = 0; p < 8; ++p)
                    acc[p] = __builtin_amdgcn_mfma_f32_16x16x32_bf16(
                        a, bfrag[s][p], acc[p], 0, 0, 0);
            }

            if (j < 7) {  // stage word j+1 (wave-private: no barrier needed)
#pragma unroll
                for (int q = 0; q < 4; ++q)
                    *(short8*)&bufN[(quad + 4 * q + 1) * XS + m * 8] = g[q];
                if (j < 6) {
#pragma unroll
                    for (int q = 0; q < 4; ++q) nidx[q] = tindx[q];
                }
            }

            // epilogue: max over 16 c-rows, +bias, store out1[b][dout][l]
            int l = (w0 + j) & 255;
            float* obase = out + OUT_PLANE + b * (ND * NL) + l;
#pragma unroll
            for (int p = 0; p < 8; ++p) {
                float v = fmaxf(fmaxf(acc[p].x, acc[p].y),
                                fmaxf(acc[p].z, acc[p].w));
                v = fmaxf(v, __shfl_xor(v, 16, 64));
                v = fmaxf(v, __shfl_xor(v, 32, 64));
                if (quad == 0)
                    obase[(p * 16 + m) * NL] = v + biasC[p * 16 + m];
            }
        }
    } else {
        // ------------------------- word path -------------------------------
        const int b = bid >> 4, l0 = (bid & 15) << 4;
        short8 bfrag[12][8];
#pragma unroll
        for (int s = 0; s < 12; ++s)
#pragma unroll
            for (int p = 0; p < 8; ++p)
                bfrag[s][p] = *(const short8*)(
                    ws + FR_WORD + (((s * 8 + p) * 64 + lane) << 3));

        // stage 18 rows x 16 chunks = 288 jobs of 16B (fp32 -> bf16)
#pragma unroll
        for (int q = 0; q < 5; ++q) {
            int jj = lane + 64 * q;
            if (jj < 288) {
                int row = jj >> 4, sub = jj & 15;
                int l = l0 + row - 1;
                int idx = (l >= 0 && l < NL) ? wv[b * NL + l] : 0;  // row0=0s
                const float4_t* src =
                    (const float4_t*)(wordT + idx * 128 + sub * 8);
                float4_t f0 = src[0], f1 = src[1];
                unsigned short t16[8];
                t16[0]=f2bf(f0.x); t16[1]=f2bf(f0.y);
                t16[2]=f2bf(f0.z); t16[3]=f2bf(f0.w);
                t16[4]=f2bf(f1.x); t16[5]=f2bf(f1.y);
                t16[6]=f2bf(f1.z); t16[7]=f2bf(f1.w);
                *(short8*)&Xs[row * XS + sub * 8] = *(const short8*)t16;
            }
        }
        // single wave: DS pipe is in-order + compiler waitcnt -> no barrier

        float4_t acc[8];
#pragma unroll
        for (int p = 0; p < 8; ++p) acc[p] = (float4_t){0.f,0.f,0.f,0.f};
#pragma unroll
        for (int s = 0; s < 12; ++s) {
            short8 a = *(const short8*)&Xs[(m + (s >> 2)) * XS +
                                           (s & 3) * 32 + quad * 8];
#pragma unroll
            for (int p = 0; p < 8; ++p)
                acc[p] = __builtin_amdgcn_mfma_f32_16x16x32_bf16(
                    a, bfrag[s][p], acc[p], 0, 0, 0);
        }

        // D[row = l_local = quad*4+reg][col = dout_local = m]; 4 l's per lane
        float* obase = out + b * (ND * NL) + l0 + quad * 4;
#pragma unroll
        for (int p = 0; p < 8; ++p) {
            float bw = biasW[p * 16 + m];
            float4_t pk;
            pk.x = acc[p].x + bw;
            pk.y = acc[p].y + bw;
            pk.z = acc[p].z + bw;
            pk.w = acc[p].w + bw;
            *(float4_t*)&obase[(p * 16 + m) * NL] = pk;
        }
    }
}

extern "C" void kernel_launch(void* const* d_in, const int* in_sizes, int n_in,
                              void* d_out, int out_size, void* d_ws,
                              size_t ws_size, hipStream_t stream) {
    const int* word_vector   = (const int*)d_in[0];
    const int* words_in_char = (const int*)d_in[1];
    const float* word_table  = (const float*)d_in[2];
    const float* chr_table   = (const float*)d_in[3];
    const float* conv_chr_w  = (const float*)d_in[4];
    const float* conv_chr_b  = (const float*)d_in[5];
    const float* conv_word_w = (const float*)d_in[6];
    const float* conv_word_b = (const float*)d_in[7];
    float* out            = (float*)d_out;
    unsigned short* wsp   = (unsigned short*)d_ws;  // frags + bf16 chr_table

    make_frags<<<448, 256, 0, stream>>>(conv_chr_w, conv_word_w, chr_table, wsp);
    conv_kernel<<<1536, 64, 0, stream>>>(word_vector, words_in_char,
                                         word_table, wsp,
                                         conv_chr_b, conv_word_b, out);
}

// Round 8
// 105.399 us; speedup vs baseline: 1.1317x; 1.1317x over previous
//
#include <hip/hip_runtime.h>

typedef __attribute__((ext_vector_type(8))) short short8;
typedef __attribute__((ext_vector_type(2))) float float2_t;
typedef __attribute__((ext_vector_type(4))) float float4_t;
typedef __attribute__((ext_vector_type(16))) float float16_t;

#define NB 32
#define NL 256
#define ND 128
#define OUT_PLANE (NB * ND * NL)   // elements per stacked output plane
#define XS 136                     // LDS row stride (bf16): conflict-free b128
#define BUFSZ (18 * XS)
#define FR_WORD 49152              // word-frag offset in ws (bf16 units)
#define CHRB 98304                 // bf16 chr_table offset in ws (bf16 units)

__device__ inline unsigned short f2bf(float f) {
    union { float f; unsigned int i; } c;
    c.f = f;
    unsigned int r = c.i + 0x7FFFu + ((c.i >> 16) & 1u);  // RN-even
    return (unsigned short)(r >> 16);
}

// ---------------------------------------------------------------------------
// ws prep:
//  [0..49151]      char B-frags for 32x32x16: frag[s][nt][lane][j],
//                  s=0..23 (k-step of 16), nt=0..3 (32-wide dout tile).
//                  B[kk][n]: n=lane&31, kk=s*16+(lane>>5)*8+j; t=kk>>7,
//                  d=kk&127; value = Wc[dout][d][t].
//  [49152..98303]  word B-frags for 16x16x32 (unchanged R6 layout).
//  [98304..114687] chr_table converted to bf16 (row 0 stays all-zero).
// ---------------------------------------------------------------------------
__global__ void make_frags(const float* __restrict__ Wc,
                           const float* __restrict__ Ww,
                           const float* __restrict__ chrT,
                           unsigned short* __restrict__ out) {
    int i = blockIdx.x * 256 + threadIdx.x;            // 0..114687
    if (i < FR_WORD) {                                 // char 32x32 frags
        int j    = i & 7;
        int lane = (i >> 3) & 63;
        int nt   = (i >> 9) & 3;
        int s    = i >> 11;                            // 0..23
        int dout = nt * 32 + (lane & 31);
        int kk   = s * 16 + ((lane >> 5) & 1) * 8 + j;
        int t    = kk >> 7;
        int d    = kk & 127;
        out[i] = f2bf(Wc[(dout * 128 + d) * 3 + t]);
    } else if (i < CHRB) {                             // word 16x16 frags
        int ii = i - FR_WORD;
        int j    = ii & 7;
        int lane = (ii >> 3) & 63;
        int nt   = (ii >> 9) & 7;
        int s    = ii >> 12;
        int dout = nt * 16 + (lane & 15);
        int t    = s >> 2;
        int k    = (s & 3) * 32 + ((lane >> 4) & 3) * 8 + j;
        out[i] = f2bf(Ww[(dout * 128 + k) * 3 + t]);
    } else {
        int j = i - CHRB;                              // 0..16383
        out[i] = f2bf(chrT[j]);
    }
}

// ---------------------------------------------------------------------------
// Merged conv kernel. Blocks 0..511: word path (16x16x32, 16 l per block).
// Blocks 512..1535: char path: 8 words as 4 PAIRS; each pair computed with
// dual-word 32x32x16 MFMA (word0 = A rows 0..15, word1 = rows 16..31).
// 4 rotating LDS buffers, one barrier per pair; staging for words j+2/j+3
// issued under the two MFMA half-blocks. 128 thr = 2 waves; wave covers
// dout ntiles {wave*2, wave*2+1} (32 wide each).
// ---------------------------------------------------------------------------
__global__ __launch_bounds__(128, 2) void conv_kernel(
    const int* __restrict__ wv, const int* __restrict__ wic,
    const float* __restrict__ wordT,
    const unsigned short* __restrict__ ws,
    const float* __restrict__ biasC, const float* __restrict__ biasW,
    float* __restrict__ out) {
    __shared__ unsigned short X[4][BUFSZ];
    const int tid  = threadIdx.x;
    const int wave = tid >> 6, lane = tid & 63;
    const int bid = blockIdx.x;

    if (bid >= 512) {
        // ------------------------- char path -------------------------------
        const unsigned short* chrB = ws + CHRB;
        const int w0 = (bid - 512) * 8;        // 8 consecutive words, same b
        const int b = w0 >> 8, l0 = w0 & 255;
        const int n32 = lane & 31;             // output col within ntile
        const int h   = (lane >> 5) & 1;       // k-half
        const int r15 = lane & 15;             // c-position within word
        const int wsel = (lane >> 4) & 1;      // 0: word j, 1: word j+1

        short8 bfrag[24][2];
#pragma unroll
        for (int s = 0; s < 24; ++s)
#pragma unroll
            for (int p = 0; p < 2; ++p)
                bfrag[s][p] = *(const short8*)(
                    ws + (((s * 4 + wave * 2 + p) * 64 + lane) << 3));

        // zero pad rows (c=-1 and c=16) in all 4 buffers; never overwritten
        for (int p = tid; p < XS; p += 128)
#pragma unroll
            for (int q = 0; q < 4; ++q) { X[q][p] = 0; X[q][17 * XS + p] = 0; }

        // staging map: 256 jobs/word = 16 rows x 16 chunks of 8 shorts (16B);
        // thread stages rows ra, ra+8 at chunk sub
        const int ra = tid >> 4, sub = tid & 15;

        // prologue: stage words 0,1 into X[0],X[1]
#pragma unroll
        for (int q = 0; q < 2; ++q) {
            int j0 = wic[(w0 + q) * 16 + ra];
            int j1 = wic[(w0 + q) * 16 + ra + 8];
            short8 g0 = *(const short8*)(chrB + j0 * 128 + sub * 8);
            short8 g1 = *(const short8*)(chrB + j1 * 128 + sub * 8);
            *(short8*)&X[q][(ra + 1) * XS + sub * 8] = g0;
            *(short8*)&X[q][(ra + 9) * XS + sub * 8] = g1;
        }
        int iA0 = wic[(w0 + 2) * 16 + ra];       // word j+2 idx
        int iA1 = wic[(w0 + 2) * 16 + ra + 8];
        int iC0 = wic[(w0 + 3) * 16 + ra];       // word j+3 idx
        int iC1 = wic[(w0 + 3) * 16 + ra + 8];
        __syncthreads();

#pragma unroll
        for (int j = 0; j < 8; j += 2) {         // 4 pairs
            // per-lane A source buffer: word j (lanes wsel=0) / j+1 (wsel=1)
            const unsigned short* abuf = X[(j + wsel) & 3];

            // issue staging loads for word j+2 (hidden under MFMA half 1)
            short8 g0, g1;
            if (j < 6) {
                g0 = *(const short8*)(chrB + iA0 * 128 + sub * 8);
                g1 = *(const short8*)(chrB + iA1 * 128 + sub * 8);
            }

            float16_t acc[2];
#pragma unroll
            for (int p = 0; p < 2; ++p)
#pragma unroll
                for (int e = 0; e < 16; ++e) acc[p][e] = 0.f;

#pragma unroll
            for (int s = 0; s < 12; ++s) {       // MFMA half 1 (t=0, t=1a)
                short8 a = *(const short8*)&abuf[(r15 + (s >> 3)) * XS +
                                                 (s & 7) * 16 + h * 8];
#pragma unroll
                for (int p = 0; p < 2; ++p)
                    acc[p] = __builtin_amdgcn_mfma_f32_32x32x16_bf16(
                        a, bfrag[s][p], acc[p], 0, 0, 0);
            }

            short8 h0, h1;
            if (j < 6) {   // write word j+2; load word j+3 under half 2
                *(short8*)&X[(j + 2) & 3][(ra + 1) * XS + sub * 8] = g0;
                *(short8*)&X[(j + 2) & 3][(ra + 9) * XS + sub * 8] = g1;
                h0 = *(const short8*)(chrB + iC0 * 128 + sub * 8);
                h1 = *(const short8*)(chrB + iC1 * 128 + sub * 8);
                if (j < 4) {   // prefetch idx for words j+4, j+5
                    iA0 = wic[(w0 + j + 4) * 16 + ra];
                    iA1 = wic[(w0 + j + 4) * 16 + ra + 8];
                    iC0 = wic[(w0 + j + 5) * 16 + ra];
                    iC1 = wic[(w0 + j + 5) * 16 + ra + 8];
                }
            }

#pragma unroll
            for (int s = 12; s < 24; ++s) {      // MFMA half 2 (t=1b, t=2)
                short8 a = *(const short8*)&abuf[(r15 + (s >> 3)) * XS +
                                                 (s & 7) * 16 + h * 8];
#pragma unroll
                for (int p = 0; p < 2; ++p)
                    acc[p] = __builtin_amdgcn_mfma_f32_32x32x16_bf16(
                        a, bfrag[s][p], acc[p], 0, 0, 0);
            }

            if (j < 6) {
                *(short8*)&X[(j + 3) & 3][(ra + 1) * XS + sub * 8] = h0;
                *(short8*)&X[(j + 3) & 3][(ra + 9) * XS + sub * 8] = h1;
            }

            // epilogue: C/D rows = c (word0: regs 0..7, word1: regs 8..15);
            // col = lane&31. xor-32 merges the two k-half row groups.
#pragma unroll
            for (int p = 0; p < 2; ++p) {
                float v0 = acc[p][0], v1 = acc[p][8];
#pragma unroll
                for (int e = 1; e < 8; ++e) {
                    v0 = fmaxf(v0, acc[p][e]);
                    v1 = fmaxf(v1, acc[p][e + 8]);
                }
                v0 = fmaxf(v0, __shfl_xor(v0, 32, 64));
                v1 = fmaxf(v1, __shfl_xor(v1, 32, 64));
                int dout = wave * 64 + p * 32 + n32;
                if (lane < 32) {
                    float bc = biasC[dout];
                    float2_t st = {v0 + bc, v1 + bc};
                    *(float2_t*)&out[OUT_PLANE + b * (ND * NL) + dout * NL +
                                     l0 + j] = st;
                }
            }
            __syncthreads();  // protects next pair's buffer overwrites
        }
    } else {
        // ------------------------- word path (16x16x32, as R6) -------------
        const int m = lane & 15, quad = lane >> 4;
        const int b = bid >> 4, l0 = (bid & 15) << 4;
        short8 bfrag[12][4];
#pragma unroll
        for (int s = 0; s < 12; ++s)
#pragma unroll
            for (int p = 0; p < 4; ++p)
                bfrag[s][p] = *(const short8*)(
                    ws + FR_WORD + (((s * 8 + wave * 4 + p) * 64 + lane) << 3));
        float bb[4];
#pragma unroll
        for (int p = 0; p < 4; ++p) bb[p] = biasW[wave * 64 + p * 16 + m];

#pragma unroll
        for (int i0 = 0; i0 < 2; ++i0) {   // 18 rows x 8 segs = 144 jobs
            int i = tid + i0 * 128;
            if (i < 144) {
                int rr = i >> 3, sg = i & 7;
                int l = l0 + rr - 1;
                int idx = (l >= 0 && l < NL) ? wv[b * NL + l] : 0;  // row0=0s
                const float4_t* src =
                    (const float4_t*)(wordT + idx * 128 + sg * 16);
                float4_t f0 = src[0], f1 = src[1], f2 = src[2], f3 = src[3];
                unsigned short t16[16];
                t16[0]=f2bf(f0.x); t16[1]=f2bf(f0.y); t16[2]=f2bf(f0.z); t16[3]=f2bf(f0.w);
                t16[4]=f2bf(f1.x); t16[5]=f2bf(f1.y); t16[6]=f2bf(f1.z); t16[7]=f2bf(f1.w);
                t16[8]=f2bf(f2.x); t16[9]=f2bf(f2.y); t16[10]=f2bf(f2.z); t16[11]=f2bf(f2.w);
                t16[12]=f2bf(f3.x); t16[13]=f2bf(f3.y); t16[14]=f2bf(f3.z); t16[15]=f2bf(f3.w);
                *(short8*)&X[0][rr * XS + sg * 16]     = *(const short8*)&t16[0];
                *(short8*)&X[0][rr * XS + sg * 16 + 8] = *(const short8*)&t16[8];
            }
        }
        __syncthreads();

        float4_t acc[4];
#pragma unroll
        for (int p = 0; p < 4; ++p) acc[p] = (float4_t){0.f, 0.f, 0.f, 0.f};
#pragma unroll
        for (int s = 0; s < 12; ++s) {
            short8 a = *(const short8*)&X[0][(m + (s >> 2)) * XS +
                                            (s & 3) * 32 + quad * 8];
#pragma unroll
            for (int p = 0; p < 4; ++p)
                acc[p] = __builtin_amdgcn_mfma_f32_16x16x32_bf16(
                    a, bfrag[s][p], acc[p], 0, 0, 0);
        }

        // D[row = l_local = quad*4+reg][col = dout_local = m]; 4 l's per lane
        float* obase = out + b * (ND * NL) + l0 + quad * 4;
#pragma unroll
        for (int p = 0; p < 4; ++p) {
            int dout = wave * 64 + p * 16 + m;
            float4_t pk;
            pk.x = acc[p].x + bb[p];
            pk.y = acc[p].y + bb[p];
            pk.z = acc[p].z + bb[p];
            pk.w = acc[p].w + bb[p];
            *(float4_t*)&obase[dout * NL] = pk;
        }
    }
}

extern "C" void kernel_launch(void* const* d_in, const int* in_sizes, int n_in,
                              void* d_out, int out_size, void* d_ws,
                              size_t ws_size, hipStream_t stream) {
    const int* word_vector   = (const int*)d_in[0];
    const int* words_in_char = (const int*)d_in[1];
    const float* word_table  = (const float*)d_in[2];
    const float* chr_table   = (const float*)d_in[3];
    const float* conv_chr_w  = (const float*)d_in[4];
    const float* conv_chr_b  = (const float*)d_in[5];
    const float* conv_word_w = (const float*)d_in[6];
    const float* conv_word_b = (const float*)d_in[7];
    float* out            = (float*)d_out;
    unsigned short* wsp   = (unsigned short*)d_ws;  // frags + bf16 chr_table

    make_frags<<<448, 256, 0, stream>>>(conv_chr_w, conv_word_w, chr_table, wsp);
    conv_kernel<<<1536, 128, 0, stream>>>(word_vector, words_in_char,
                                          word_table, wsp,
                                          conv_chr_b, conv_word_b, out);
}